// Round 1
// baseline (211.493 us; speedup 1.0000x reference)
//
#include <hip/hip_runtime.h>
#include <math.h>

#define B_DIM 4096
#define D_DIM 4096
#define C_DIM 1000

typedef float v4f __attribute__((ext_vector_type(4)));

// ---------------------------------------------------------------------------
// Kernel A: per-row confidence -> noise scale. One wave (64 lanes) per row,
// fully wave-synchronous: NO barriers, NO shared memory. 1024 blocks x 4 waves.
// Reads 16 MB (model_output), writes 16 KB (scales in workspace).
// ---------------------------------------------------------------------------
__global__ __launch_bounds__(256) void compute_scales(
    const float* __restrict__ mo,
    float* __restrict__ scales)
{
    const int row  = blockIdx.x * 4 + (threadIdx.x >> 6);
    const int lane = threadIdx.x & 63;
    const v4f* mo4 = (const v4f*)(mo + (size_t)row * C_DIM);

    // 250 v4f (=1000 logits) per row across 64 lanes: 64+64+64+58
    const v4f NEG = {-INFINITY, -INFINITY, -INFINITY, -INFINITY};
    const v4f a = mo4[lane];
    const v4f b = mo4[lane + 64];
    const v4f c = mo4[lane + 128];
    const v4f d = (lane < 58) ? mo4[lane + 192] : NEG;

    float lm = fmaxf(fmaxf(fmaxf(a.x, a.y), fmaxf(a.z, a.w)),
                     fmaxf(fmaxf(b.x, b.y), fmaxf(b.z, b.w)));
    lm = fmaxf(lm, fmaxf(fmaxf(c.x, c.y), fmaxf(c.z, c.w)));
    lm = fmaxf(lm, fmaxf(fmaxf(d.x, d.y), fmaxf(d.z, d.w)));
    #pragma unroll
    for (int off = 32; off > 0; off >>= 1)
        lm = fmaxf(lm, __shfl_xor(lm, off, 64));

    // exp(-inf - lm) == 0 for the masked tail lanes -> no contribution
    float ls = __expf(a.x - lm) + __expf(a.y - lm) + __expf(a.z - lm) + __expf(a.w - lm)
             + __expf(b.x - lm) + __expf(b.y - lm) + __expf(b.z - lm) + __expf(b.w - lm)
             + __expf(c.x - lm) + __expf(c.y - lm) + __expf(c.z - lm) + __expf(c.w - lm)
             + __expf(d.x - lm) + __expf(d.y - lm) + __expf(d.z - lm) + __expf(d.w - lm);
    #pragma unroll
    for (int off = 32; off > 0; off >>= 1)
        ls += __shfl_xor(ls, off, 64);

    // confidence = max softmax prob = 1/sum(exp(l - max))
    if (lane == 0)
        scales[row] = fminf(0.1f * (1.0f + 1.0f / ls), 1.0f);
}

// ---------------------------------------------------------------------------
// Kernel B: pure streaming masked-add. One block per row; no barriers, no
// cross-lane ops, no dependent prologue. The per-row scale is a single
// uniform scalar load that only feeds the FMA, so all 12 stream loads issue
// immediately. Nontemporal loads (streaming, no reuse); stores stay normal
// (nontemporal stores raced the harness poison in the prior session, R3).
// ---------------------------------------------------------------------------
__global__ __launch_bounds__(256) void stream_add(
    const float* __restrict__ x,
    const float* __restrict__ rand_u,
    const float* __restrict__ noise_std,
    const float* __restrict__ scales,
    float* __restrict__ out)
{
    const int b = blockIdx.x;
    const int t = threadIdx.x;
    const float scale = scales[b];

    const size_t rowf4 = (size_t)b * (D_DIM / 4);
    const v4f* x4 = (const v4f*)x         + rowf4;
    const v4f* r4 = (const v4f*)rand_u    + rowf4;
    const v4f* n4 = (const v4f*)noise_std + rowf4;
    v4f*       o4 = (v4f*)out             + rowf4;

    #pragma unroll
    for (int k = 0; k < 4; ++k) {
        const int idx = k * 256 + t;
        const v4f xv = __builtin_nontemporal_load(x4 + idx);
        const v4f rv = __builtin_nontemporal_load(r4 + idx);
        const v4f nv = __builtin_nontemporal_load(n4 + idx);
        v4f ov;
        ov.x = xv.x + (rv.x < 0.3f ? nv.x * scale : 0.0f);
        ov.y = xv.y + (rv.y < 0.3f ? nv.y * scale : 0.0f);
        ov.z = xv.z + (rv.z < 0.3f ? nv.z * scale : 0.0f);
        ov.w = xv.w + (rv.w < 0.3f ? nv.w * scale : 0.0f);
        o4[idx] = ov;
    }
}

extern "C" void kernel_launch(void* const* d_in, const int* in_sizes, int n_in,
                              void* d_out, int out_size, void* d_ws, size_t ws_size,
                              hipStream_t stream) {
    const float* x            = (const float*)d_in[0];
    const float* model_output = (const float*)d_in[1];
    const float* rand_u       = (const float*)d_in[2];
    const float* noise_std    = (const float*)d_in[3];
    float* out    = (float*)d_out;
    float* scales = (float*)d_ws;   // 4096 floats = 16 KB

    compute_scales<<<B_DIM / 4, 256, 0, stream>>>(model_output, scales);
    stream_add<<<B_DIM, 256, 0, stream>>>(x, rand_u, noise_std, scales, out);
}

// Round 2
// 209.400 us; speedup vs baseline: 1.0100x; 1.0100x over previous
//
#include <hip/hip_runtime.h>
#include <math.h>

#define B_DIM 4096
#define D_DIM 4096
#define C_DIM 1000

typedef float v4f __attribute__((ext_vector_type(4)));

// ---------------------------------------------------------------------------
// One fused, barrier-free kernel. One block per row (4096 blocks x 256 thr).
//
// Each WAVE redundantly computes the row's softmax confidence from the 1000
// logits (4 v4f per lane, wave-local shuffle reductions) — no LDS, no
// __syncthreads, so no vmcnt(0) barrier-drain anywhere in the kernel.
//
// Load-issue order is chosen for the vmcnt queue:
//   1) 4 logit loads (oldest — needed first, for the reduction)
//   2) all 12 stream loads (x, rand_u, noise_std)
//   3) reduction waits vmcnt(12): logits arrived, stream loads STAY in flight
//   4) compute + store drains the stream loads group by group
// This keeps 12 v4f loads/thread outstanding under the softmax latency
// (round-1 kernel had VGPR=28 => compiler had serialized them into chunks).
//
// mo uses plain loads (row re-read by 4 waves -> L1 reuse); the three
// streamed arrays use nontemporal loads (single-use, no-allocate).
// Stores stay normal (nontemporal stores raced the harness poison — R3).
// ---------------------------------------------------------------------------
__global__ __launch_bounds__(256) void adaptive_noise_onepass(
    const float* __restrict__ x,
    const float* __restrict__ mo,
    const float* __restrict__ rand_u,
    const float* __restrict__ noise_std,
    float* __restrict__ out)
{
    const int b    = blockIdx.x;
    const int t    = threadIdx.x;
    const int lane = t & 63;

    // ---- 1) issue logit loads (250 v4f = 1000 logits; 64+64+64+58 lanes) ----
    const v4f* mo4 = (const v4f*)(mo + (size_t)b * C_DIM);
    const v4f NEG = {-INFINITY, -INFINITY, -INFINITY, -INFINITY};
    const v4f la = mo4[lane];
    const v4f lb = mo4[lane + 64];
    const v4f lc = mo4[lane + 128];
    v4f ld = NEG;
    if (lane < 58) ld = mo4[lane + 192];

    // ---- 2) issue ALL stream loads before any use of the logits ----
    const size_t rowf4 = (size_t)b * (D_DIM / 4);
    const v4f* x4 = (const v4f*)x         + rowf4;
    const v4f* r4 = (const v4f*)rand_u    + rowf4;
    const v4f* n4 = (const v4f*)noise_std + rowf4;
    v4f*       o4 = (v4f*)out             + rowf4;

    v4f xv[4], rv[4], nv[4];
    #pragma unroll
    for (int k = 0; k < 4; ++k) {
        const int idx = k * 256 + t;
        xv[k] = __builtin_nontemporal_load(x4 + idx);
        rv[k] = __builtin_nontemporal_load(r4 + idx);
        nv[k] = __builtin_nontemporal_load(n4 + idx);
    }

    // ---- 3) wave-local softmax reduction (waits only on the logit loads) ----
    float lm = fmaxf(fmaxf(fmaxf(la.x, la.y), fmaxf(la.z, la.w)),
                     fmaxf(fmaxf(lb.x, lb.y), fmaxf(lb.z, lb.w)));
    lm = fmaxf(lm, fmaxf(fmaxf(lc.x, lc.y), fmaxf(lc.z, lc.w)));
    lm = fmaxf(lm, fmaxf(fmaxf(ld.x, ld.y), fmaxf(ld.z, ld.w)));
    #pragma unroll
    for (int off = 32; off > 0; off >>= 1)
        lm = fmaxf(lm, __shfl_xor(lm, off, 64));

    // exp(-inf - lm) == 0 for masked tail lanes -> no contribution
    float ls = __expf(la.x - lm) + __expf(la.y - lm) + __expf(la.z - lm) + __expf(la.w - lm)
             + __expf(lb.x - lm) + __expf(lb.y - lm) + __expf(lb.z - lm) + __expf(lb.w - lm)
             + __expf(lc.x - lm) + __expf(lc.y - lm) + __expf(lc.z - lm) + __expf(lc.w - lm)
             + __expf(ld.x - lm) + __expf(ld.y - lm) + __expf(ld.z - lm) + __expf(ld.w - lm);
    #pragma unroll
    for (int off = 32; off > 0; off >>= 1)
        ls += __shfl_xor(ls, off, 64);

    // confidence = max softmax prob = 1/sum(exp(l - max))
    const float scale = fminf(0.1f * (1.0f + 1.0f / ls), 1.0f);

    // ---- 4) masked add + store (drains stream loads group by group) ----
    #pragma unroll
    for (int k = 0; k < 4; ++k) {
        const int idx = k * 256 + t;
        v4f ov;
        ov.x = xv[k].x + (rv[k].x < 0.3f ? nv[k].x * scale : 0.0f);
        ov.y = xv[k].y + (rv[k].y < 0.3f ? nv[k].y * scale : 0.0f);
        ov.z = xv[k].z + (rv[k].z < 0.3f ? nv[k].z * scale : 0.0f);
        ov.w = xv[k].w + (rv[k].w < 0.3f ? nv[k].w * scale : 0.0f);
        o4[idx] = ov;
    }
}

extern "C" void kernel_launch(void* const* d_in, const int* in_sizes, int n_in,
                              void* d_out, int out_size, void* d_ws, size_t ws_size,
                              hipStream_t stream) {
    const float* x            = (const float*)d_in[0];
    const float* model_output = (const float*)d_in[1];
    const float* rand_u       = (const float*)d_in[2];
    const float* noise_std    = (const float*)d_in[3];
    float* out = (float*)d_out;

    adaptive_noise_onepass<<<B_DIM, 256, 0, stream>>>(
        x, model_output, rand_u, noise_std, out);
}

// Round 3
// 209.270 us; speedup vs baseline: 1.0106x; 1.0006x over previous
//
#include <hip/hip_runtime.h>
#include <math.h>

#define B_DIM 4096
#define D_DIM 4096
#define C_DIM 1000

typedef float v4f __attribute__((ext_vector_type(4)));

// ---------------------------------------------------------------------------
// Fused, barrier-free, ISSUE-ORDER-PINNED kernel. One block per row.
//
// Round-2 failure: VGPR_Count=32 proved the machine scheduler sank the 12
// stream loads to their uses (reg-pressure heuristic), so each block's
// stream traffic waited behind the softmax prologue (logit load + 2 shuffle
// trees). Fix: issue logits first (oldest in the vmcnt FIFO), then ALL 12
// stream loads, then __builtin_amdgcn_sched_barrier(0) — a hard scheduling
// fence nothing crosses. The softmax then waits only vmcnt(12): logits have
// arrived, the 12 stream loads STAY in flight and drain under the softmax.
//
// No LDS, no __syncthreads anywhere -> no vmcnt(0) barrier drain.
// The lane<58 tail is handled branch-free (clamped addr + cndmask) so the
// entire load sequence is one straight-line scheduling region.
//
// mo: plain loads (row re-read by 4 waves -> cache reuse). Streams:
// nontemporal (single-use, no-allocate; preserves harness-warm L3 lines).
// Stores: normal (nontemporal stores raced the harness poison — prior R3).
// ---------------------------------------------------------------------------
__global__ __launch_bounds__(256) void adaptive_noise_pinned(
    const float* __restrict__ x,
    const float* __restrict__ mo,
    const float* __restrict__ rand_u,
    const float* __restrict__ noise_std,
    float* __restrict__ out)
{
    const int b    = blockIdx.x;
    const int t    = threadIdx.x;
    const int lane = t & 63;

    // ---- 1) logit loads first: oldest entries in the vmcnt queue ----
    const v4f* mo4 = (const v4f*)(mo + (size_t)b * C_DIM);
    const v4f la = mo4[lane];
    const v4f lb = mo4[lane + 64];
    const v4f lc = mo4[lane + 128];
    const int dIdx = (lane < 58) ? (lane + 192) : 249;   // clamped, branch-free
    const v4f ldr = mo4[dIdx];

    // ---- 2) all 12 stream loads issued before any logit use ----
    const size_t rowf4 = (size_t)b * (D_DIM / 4);
    const v4f* x4 = (const v4f*)x         + rowf4;
    const v4f* r4 = (const v4f*)rand_u    + rowf4;
    const v4f* n4 = (const v4f*)noise_std + rowf4;
    v4f*       o4 = (v4f*)out             + rowf4;

    v4f xv[4], rv[4], nv[4];
    #pragma unroll
    for (int k = 0; k < 4; ++k) {
        const int idx = k * 256 + t;
        xv[k] = __builtin_nontemporal_load(x4 + idx);
        rv[k] = __builtin_nontemporal_load(r4 + idx);
        nv[k] = __builtin_nontemporal_load(n4 + idx);
    }

    // ---- 3) hard scheduling fence: loads above may NOT sink below ----
    __builtin_amdgcn_sched_barrier(0);

    // ---- 4) wave-local softmax (waits vmcnt(12): only the logits) ----
    const float NEG = -INFINITY;
    v4f ld;
    ld.x = (lane < 58) ? ldr.x : NEG;
    ld.y = (lane < 58) ? ldr.y : NEG;
    ld.z = (lane < 58) ? ldr.z : NEG;
    ld.w = (lane < 58) ? ldr.w : NEG;

    float lm = fmaxf(fmaxf(fmaxf(la.x, la.y), fmaxf(la.z, la.w)),
                     fmaxf(fmaxf(lb.x, lb.y), fmaxf(lb.z, lb.w)));
    lm = fmaxf(lm, fmaxf(fmaxf(lc.x, lc.y), fmaxf(lc.z, lc.w)));
    lm = fmaxf(lm, fmaxf(fmaxf(ld.x, ld.y), fmaxf(ld.z, ld.w)));
    #pragma unroll
    for (int off = 32; off > 0; off >>= 1)
        lm = fmaxf(lm, __shfl_xor(lm, off, 64));

    // exp(-inf - lm) == 0 for masked tail lanes -> no contribution
    float ls = __expf(la.x - lm) + __expf(la.y - lm) + __expf(la.z - lm) + __expf(la.w - lm)
             + __expf(lb.x - lm) + __expf(lb.y - lm) + __expf(lb.z - lm) + __expf(lb.w - lm)
             + __expf(lc.x - lm) + __expf(lc.y - lm) + __expf(lc.z - lm) + __expf(lc.w - lm)
             + __expf(ld.x - lm) + __expf(ld.y - lm) + __expf(ld.z - lm) + __expf(ld.w - lm);
    #pragma unroll
    for (int off = 32; off > 0; off >>= 1)
        ls += __shfl_xor(ls, off, 64);

    // confidence = max softmax prob = 1/sum(exp(l - max))
    const float scale = fminf(0.1f * (1.0f + 1.0f / ls), 1.0f);

    // ---- 5) masked add + store (drains the in-flight stream loads) ----
    #pragma unroll
    for (int k = 0; k < 4; ++k) {
        const int idx = k * 256 + t;
        v4f ov;
        ov.x = xv[k].x + (rv[k].x < 0.3f ? nv[k].x * scale : 0.0f);
        ov.y = xv[k].y + (rv[k].y < 0.3f ? nv[k].y * scale : 0.0f);
        ov.z = xv[k].z + (rv[k].z < 0.3f ? nv[k].z * scale : 0.0f);
        ov.w = xv[k].w + (rv[k].w < 0.3f ? nv[k].w * scale : 0.0f);
        o4[idx] = ov;
    }
}

extern "C" void kernel_launch(void* const* d_in, const int* in_sizes, int n_in,
                              void* d_out, int out_size, void* d_ws, size_t ws_size,
                              hipStream_t stream) {
    const float* x            = (const float*)d_in[0];
    const float* model_output = (const float*)d_in[1];
    const float* rand_u       = (const float*)d_in[2];
    const float* noise_std    = (const float*)d_in[3];
    float* out = (float*)d_out;

    adaptive_noise_pinned<<<B_DIM, 256, 0, stream>>>(
        x, model_output, rand_u, noise_std, out);
}